// Round 3
// baseline (136.164 us; speedup 1.0000x reference)
//
#include <hip/hip_runtime.h>
#include <hip/hip_bf16.h>

typedef __attribute__((ext_vector_type(8))) short bf16x8;
typedef __attribute__((ext_vector_type(4))) float f32x4;
typedef __attribute__((ext_vector_type(4))) int   i32x4;
typedef __attribute__((ext_vector_type(2))) int   i32x2;

#define DEV static __device__ __forceinline__

DEV unsigned short f2bf(float f) {
  __hip_bfloat16 h = __float2bfloat16(f);
  return __builtin_bit_cast(unsigned short, h);
}
DEV int pack2(float a, float b) {
  return (int)f2bf(a) | ((int)f2bf(b) << 16);
}
DEV bf16x8 ldsFrag(const char* lds, int off) {
  i32x4 v = *(const i32x4*)(lds + off);
  return __builtin_bit_cast(bf16x8, v);
}

// ---------------- pre-kernel 1: x [16][512][256] f32 -> xt [16][256][512] bf16 (transpose+cvt)
__global__ __launch_bounds__(256) void cvt_x_transpose(
    const float* __restrict__ x, unsigned short* __restrict__ xt)
{
  __shared__ unsigned short lt[64][72];
  const int bc = blockIdx.z;      // 16
  const int mt = blockIdx.y;      // 8  -> m0 = mt*64
  const int ut = blockIdx.x;      // 4  -> u0 = ut*64
  const int tid = threadIdx.x;
  const int ul = tid & 63;
  const int mr = tid >> 6;        // 0..3
  const float* px = x + ((size_t)bc * 512 + mt * 64) * 256 + ut * 64;
#pragma unroll
  for (int r = 0; r < 16; r++) {
    int m = r * 4 + mr;
    lt[m][ul] = f2bf(px[(size_t)m * 256 + ul]);
  }
  __syncthreads();
  const int urow = tid >> 2;      // 0..63
  const int mq = tid & 3;         // 16 m each
  unsigned short* po = xt + ((size_t)bc * 256 + ut * 64 + urow) * 512 + mt * 64 + mq * 16;
  int w[8];
#pragma unroll
  for (int j = 0; j < 8; j++) {
    unsigned short a = lt[mq * 16 + 2 * j][urow];
    unsigned short b = lt[mq * 16 + 2 * j + 1][urow];
    w[j] = (int)a | ((int)b << 16);
  }
  ((i32x4*)po)[0] = i32x4{w[0], w[1], w[2], w[3]};
  ((i32x4*)po)[1] = i32x4{w[4], w[5], w[6], w[7]};
}

// ---------------- pre-kernel 2: streaming f32->bf16 for sw (1M el) then tw (256K el)
__global__ __launch_bounds__(256) void cvt_stream(
    const float* __restrict__ sw, unsigned short* __restrict__ swb,
    const float* __restrict__ tw, unsigned short* __restrict__ twb)
{
  int i = blockIdx.x * 256 + threadIdx.x;   // grid 640 blocks: 512 for sw, 128 for tw
  const float* in;
  unsigned short* o;
  if (i < 131072) { in = sw; o = swb; }
  else            { in = tw; o = twb; i -= 131072; }
  const f32x4* p = (const f32x4*)(in + (size_t)i * 8);
  f32x4 a = p[0], b = p[1];
  i32x4 w;
  w[0] = pack2(a[0], a[1]); w[1] = pack2(a[2], a[3]);
  w[2] = pack2(b[0], b[1]); w[3] = pack2(b[2], b[3]);
  *(i32x4*)(o + (size_t)i * 8) = w;
}

// ---------------- main fused kernel
// B=4, C=4, N=512, T=256, K(P)=4, J(Q)=4
// Block = (bc, p, n-tile of 128). Grid 256, 512 threads (1 block/CU).
// Stage A: tmp[n][u] = sum_m S_p[n0+n][m] * X[m][u]  (acc = tmp^T frags),
//          A/B frags loaded DIRECTLY from bf16 global (xt transposed, swb) — no LDS, no barrier.
// Stage B: y[n][t] = sum_u tmp[n][u] * T_q[t][u] -> relu(y), relu(-y), non-temporal stores.
__global__ __launch_bounds__(512, 2) void stblis_main(
    const unsigned short* __restrict__ xt, const unsigned short* __restrict__ swb,
    const unsigned short* __restrict__ twb, float* __restrict__ out)
{
  constexpr int N = 512, T = 256;
  // LDS: tmp[n=128][u=256] bf16, row 512B, slot s=(u>>3)^(n&7)
  __shared__ __align__(16) char lds[65536];

  const int tid  = threadIdx.x;
  const int lane = tid & 63;
  const int wid  = tid >> 6;
  const int l15  = lane & 15;
  const int l4   = lane >> 4;

  const int bx = blockIdx.x;
  const int nt = bx & 3;
  const int p  = (bx >> 2) & 3;
  const int bc = bx >> 4;        // b*4 + c
  const int n0 = nt * 128;

  const unsigned short* __restrict__ Xu = xt  + (size_t)bc * (256 * 512);      // [u][m]
  const unsigned short* __restrict__ Sn = swb + (size_t)p * (N * N) + (size_t)n0 * N;

  // ---------------- stage A ----------------
  const int wu = wid >> 1;   // u block (64)
  const int wn = wid & 1;    // n block (64)

  f32x4 acc[4][4];
#pragma unroll
  for (int i = 0; i < 4; i++)
#pragma unroll
    for (int j = 0; j < 4; j++) acc[i][j] = {0.f, 0.f, 0.f, 0.f};

  const unsigned short* pxu = Xu + (size_t)(wu * 64 + l15) * 512 + l4 * 8;
  const unsigned short* psn = Sn + (size_t)(wn * 64 + l15) * 512 + l4 * 8;

  for (int kc = 0; kc < 8; kc++) {
#pragma unroll
    for (int ks = 0; ks < 2; ks++) {
      const int mofs = kc * 64 + ks * 32;
      bf16x8 af[4], bg[4];
#pragma unroll
      for (int uf = 0; uf < 4; uf++)
        af[uf] = *(const bf16x8*)(pxu + (size_t)uf * 16 * 512 + mofs);
#pragma unroll
      for (int nf = 0; nf < 4; nf++)
        bg[nf] = *(const bf16x8*)(psn + (size_t)nf * 16 * 512 + mofs);
#pragma unroll
      for (int uf = 0; uf < 4; uf++)
#pragma unroll
        for (int nf = 0; nf < 4; nf++)
          acc[uf][nf] = __builtin_amdgcn_mfma_f32_16x16x32_bf16(
              af[uf], bg[nf], acc[uf][nf], 0, 0, 0);
    }
  }

  // acc (tmp^T fragments) -> LDS tmp[n][u] bf16; C-frag regs are 4 consecutive u
#pragma unroll
  for (int uf = 0; uf < 4; uf++)
#pragma unroll
    for (int nf = 0; nf < 4; nf++) {
      int u0 = wu * 64 + uf * 16 + l4 * 4;
      int n  = wn * 64 + nf * 16 + l15;
      i32x2 w;
      w[0] = pack2(acc[uf][nf][0], acc[uf][nf][1]);
      w[1] = pack2(acc[uf][nf][2], acc[uf][nf][3]);
      *(i32x2*)(lds + n * 512 + (((u0 >> 3) ^ (n & 7)) << 4) + (u0 & 7) * 2) = w;
    }
  __syncthreads();

  // ---------------- stage B ----------------
  const int q  = wid >> 1;
  const int nh = wid & 1;
  const unsigned short* __restrict__ Tq = twb + (size_t)q * (T * T);  // [t][u] bf16
  const int b = bc >> 2, c = bc & 3;
  const int ch = c * 16 + p * 4 + q;          // in [0,64)
  float* __restrict__ outP = out + ((size_t)(b * 128 + ch) * N + n0) * T;
  float* __restrict__ outN = outP + (size_t)64 * N * T;   // negative half

  for (int tc = 0; tc < 4; tc++) {
    f32x4 a2[4][4];
#pragma unroll
    for (int i = 0; i < 4; i++)
#pragma unroll
      for (int j = 0; j < 4; j++) a2[i][j] = {0.f, 0.f, 0.f, 0.f};

#pragma unroll
    for (int us = 0; us < 8; us++) {
      const int slot = us * 4 + l4;    // u-slot 0..31
      bf16x8 af[4], bg[4];
#pragma unroll
      for (int nf = 0; nf < 4; nf++) {
        int n = nh * 64 + nf * 16 + l15;
        af[nf] = ldsFrag(lds, n * 512 + ((slot ^ (n & 7)) << 4));
      }
#pragma unroll
      for (int tf = 0; tf < 4; tf++) {
        int t = tc * 64 + tf * 16 + l15;
        bg[tf] = *(const bf16x8*)(Tq + (size_t)t * T + slot * 8);
      }
#pragma unroll
      for (int nf = 0; nf < 4; nf++)
#pragma unroll
        for (int tf = 0; tf < 4; tf++)
          a2[nf][tf] = __builtin_amdgcn_mfma_f32_16x16x32_bf16(
              af[nf], bg[tf], a2[nf][tf], 0, 0, 0);
    }

    // dual-ReLU epilogue, non-temporal (output never re-read; keep L2 for inputs)
#pragma unroll
    for (int nf = 0; nf < 4; nf++) {
#pragma unroll
      for (int tf = 0; tf < 4; tf++) {
        int t  = tc * 64 + tf * 16 + l15;
        int nb = nh * 64 + nf * 16 + l4 * 4;
#pragma unroll
        for (int r = 0; r < 4; r++) {
          float v = a2[nf][tf][r];
          size_t o = (size_t)(nb + r) * T + t;
          __builtin_nontemporal_store(fmaxf(v, 0.f),  &outP[o]);
          __builtin_nontemporal_store(fmaxf(-v, 0.f), &outN[o]);
        }
      }
    }
  }
}

extern "C" void kernel_launch(void* const* d_in, const int* in_sizes, int n_in,
                              void* d_out, int out_size, void* d_ws, size_t ws_size,
                              hipStream_t stream) {
  (void)in_sizes; (void)n_in; (void)out_size; (void)ws_size;
  const float* x  = (const float*)d_in[0];
  const float* sw = (const float*)d_in[1];
  const float* tw = (const float*)d_in[2];
  float* out = (float*)d_out;

  // workspace layout (bf16): xt 16*256*512 = 2M el (4 MB) | swb 1M el (2 MB) | twb 256K el (0.5 MB)
  unsigned short* xt  = (unsigned short*)d_ws;
  unsigned short* swb = xt + (size_t)16 * 256 * 512;
  unsigned short* twb = swb + (size_t)4 * 512 * 512;

  cvt_x_transpose<<<dim3(4, 8, 16), dim3(256), 0, stream>>>(x, xt);
  cvt_stream<<<dim3(640), dim3(256), 0, stream>>>(sw, swb, tw, twb);
  stblis_main<<<dim3(256), dim3(512), 0, stream>>>(xt, swb, twb, out);
}